// Round 1
// baseline (69.175 us; speedup 1.0000x reference)
//
#include <hip/hip_runtime.h>
#include <hip/hip_bf16.h>

// KernalAnsatz_65481071409588
//
// Reference: |<psi_x|psi_y>|^2 with psi_a = W * RY(a)|0>, where W (the
// RX/RY/RZ layers + CNOT ring, parameterized by `params`) is IDENTICAL for
// both states. By unitary invariance W cancels in the inner product:
//
//   <psi_x|psi_y> = <0| RY(x)^† RY(y) |0> = prod_q cos((x_q - y_q)/2)
//
// so the answer is prod_q cos^2((x_q - y_q)/2). Computed in double for
// ~1e-16 relative error (threshold is ~2e-2 relative).

#define N_QUBITS 23

__global__ void KernalAnsatz_65481071409588_kernel(const float* __restrict__ x,
                                                   const float* __restrict__ y,
                                                   float* __restrict__ out) {
    if (blockIdx.x == 0 && threadIdx.x == 0) {
        double p = 1.0;
        #pragma unroll
        for (int q = 0; q < N_QUBITS; ++q) {
            double d = 0.5 * ((double)x[q] - (double)y[q]);
            double c = cos(d);
            p *= c * c;
        }
        out[0] = (float)p;
    }
}

extern "C" void kernel_launch(void* const* d_in, const int* in_sizes, int n_in,
                              void* d_out, int out_size, void* d_ws, size_t ws_size,
                              hipStream_t stream) {
    const float* x = (const float*)d_in[0];
    const float* y = (const float*)d_in[1];
    // d_in[2] = params — provably irrelevant to the output (W cancels).
    float* out = (float*)d_out;
    KernalAnsatz_65481071409588_kernel<<<1, 64, 0, stream>>>(x, y, out);
}